// Round 1
// baseline (71424.579 us; speedup 1.0000x reference)
//
#include <hip/hip_runtime.h>
#include <hip/hip_cooperative_groups.h>
#include <math.h>

namespace cg = cooperative_groups;

#define Bb   8
#define Tt   2048
#define Hh   1024
#define NWG  256
#define NTHR 256
#define KK   (2*Hh)          // dot length per output column (ih-part ++ hh-part)
#define CPW  8               // columns per workgroup
#define WPL  128             // workgroups per layer

// LDS layout (floats)
#define W_OFF    0
#define IN_OFF   (CPW*KK)            // 16384
#define RED_OFF  (IN_OFF + Bb*KK)    // 32768
#define BIAS_OFF (RED_OFF + 4*64)    // 33024
#define SMEM_FLOATS (BIAS_OFF + CPW) // 33032 -> 132128 bytes

__global__ __launch_bounds__(NTHR, 1)
void rnn_persist(const float* __restrict__ X,
                 const float* __restrict__ ihw,
                 const float* __restrict__ ihb,
                 const float* __restrict__ hhw,
                 const float* __restrict__ hhb,
                 float* __restrict__ out,
                 float* __restrict__ ws)
{
    extern __shared__ float smem[];
    float* w_lds  = smem + W_OFF;    // [8][2048]  (c-local, k)
    float* in_lds = smem + IN_OFF;   // [8][2048]  (b, k)
    float* red    = smem + RED_OFF;  // [4][64]
    float* biasl  = smem + BIAS_OFF; // [8]

    const int tid = threadIdx.x;
    const int wg  = blockIdx.x;
    const int lay = (wg >= WPL) ? 1 : 0;
    const int colbase = (wg & (WPL-1)) * CPW;

    // ---- load this WG's weight slice once: w_lds[c][k] ----
    for (int i = tid; i < CPW*(KK/4); i += NTHR) {
        const int c  = i >> 9;          // KK/4 = 512
        const int kq = i & 511;
        const int k  = kq << 2;
        const int col = colbase + c;
        const float* src = (k < Hh)
            ? (ihw + ((size_t)lay*Hh + col)*Hh + k)
            : (hhw + ((size_t)lay*Hh + col)*Hh + (k - Hh));
        *(float4*)&w_lds[c*KK + k] = *(const float4*)src;
    }
    if (tid < CPW) {
        const int col = colbase + tid;
        biasl[tid] = ihb[lay*Hh + col] + hhb[lay*Hh + col];
    }
    __syncthreads();

    float* h0buf = ws;              // [2][B][H]
    float* h1buf = ws + 2*Bb*Hh;    // [2][B][H]

    cg::grid_group grid = cg::this_grid();

    for (int p = 0; p <= Tt; ++p) {
        const int pb = p & 1, qb = (p + 1) & 1;
        const float* h0r = h0buf + (size_t)qb*Bb*Hh;  // h0(t-1) for l0 / h0(t) for l1
        float*       h0w = h0buf + (size_t)pb*Bb*Hh;
        const float* h1r = h1buf + (size_t)pb*Bb*Hh;
        float*       h1w = h1buf + (size_t)qb*Bb*Hh;

        const bool active = lay ? (p >= 1) : (p < Tt);
        const int  t      = lay ? (p - 1) : p;

        if (active) {
            // ---- stage inputs: in_lds[b][0..1023]=A, [1024..2047]=B ----
            if (lay == 0) {
                for (int i = tid; i < Bb*(Hh/4); i += NTHR) {
                    const int b = i >> 8; const int k = (i & 255) << 2;
                    *(float4*)&in_lds[b*KK + k] =
                        *(const float4*)&X[((size_t)b*Tt + t)*Hh + k];
                    *(float4*)&in_lds[b*KK + Hh + k] =
                        *(const float4*)&h0r[b*Hh + k];
                }
            } else {
                for (int i = tid; i < Bb*(Hh/4); i += NTHR) {
                    const int b = i >> 8; const int k = (i & 255) << 2;
                    *(float4*)&in_lds[b*KK + k] =
                        *(const float4*)&h0r[b*Hh + k];
                    *(float4*)&in_lds[b*KK + Hh + k] =
                        *(const float4*)&h1r[b*Hh + k];
                }
            }
            __syncthreads();

            // ---- duplication-free outer product: thread owns 8 k's ----
            float acc[8][8];
            #pragma unroll
            for (int c = 0; c < 8; ++c)
                #pragma unroll
                for (int b = 0; b < 8; ++b) acc[c][b] = 0.f;

            #pragma unroll
            for (int half = 0; half < 2; ++half) {
                const int k = half*Hh + tid*4;   // linear b128, conflict-free
                float4 wv[8], iv[8];
                #pragma unroll
                for (int c = 0; c < 8; ++c) wv[c] = *(const float4*)&w_lds[c*KK + k];
                #pragma unroll
                for (int b = 0; b < 8; ++b) iv[b] = *(const float4*)&in_lds[b*KK + k];
                #pragma unroll
                for (int c = 0; c < 8; ++c) {
                    const float4 w4 = wv[c];
                    #pragma unroll
                    for (int b = 0; b < 8; ++b) {
                        const float4 i4 = iv[b];
                        acc[c][b] += w4.x*i4.x; acc[c][b] += w4.y*i4.y;
                        acc[c][b] += w4.z*i4.z; acc[c][b] += w4.w*i4.w;
                    }
                }
            }

            // ---- intra-wave butterfly reduce: lane l ends with output o=l ----
            // o = b*8 + c so consecutive lanes -> consecutive columns on store
            float v[64];
            #pragma unroll
            for (int c = 0; c < 8; ++c)
                #pragma unroll
                for (int b = 0; b < 8; ++b) v[b*8 + c] = acc[c][b];
            const int lane = tid & 63;
            #pragma unroll
            for (int r = 0; r < 6; ++r) {
                const int bit = (lane >> r) & 1;
                #pragma unroll
                for (int j = 0; j < (64 >> (r + 1)); ++j) {
                    const float send = bit ? v[2*j]     : v[2*j + 1];
                    const float mine = bit ? v[2*j + 1] : v[2*j];
                    const float recv = __shfl_xor(send, 1 << r, 64);
                    v[j] = mine + recv;
                }
            }
            red[(tid >> 6)*64 + lane] = v[0];
            __syncthreads();

            if (tid < 64) {
                const int b = tid >> 3, c = tid & 7;
                const int col = colbase + c;
                const float s = red[tid] + red[64 + tid] + red[128 + tid]
                              + red[192 + tid] + biasl[c];
                const float val = tanhf(s);
                if (lay == 0) {
                    h0w[b*Hh + col] = val;
                } else {
                    h1w[b*Hh + col] = val;
                    out[((size_t)b*Tt + t)*Hh + col] = val;        // ys[b][t]
                    if (t == Tt - 1)
                        out[(size_t)Bb*Tt*Hh + ((size_t)Bb + b)*Hh + col] = val; // h_T[1]
                }
            }
        } else if (lay == 0 && p == Tt) {
            // final h0 -> h_T[0]  (h0(T-1) lives in buffer qb==1; own columns)
            if (tid < 64) {
                const int b = tid >> 3, c = tid & 7;
                const int col = colbase + c;
                out[(size_t)Bb*Tt*Hh + (size_t)b*Hh + col] = h0r[b*Hh + col];
            }
        }
        grid.sync();
    }
}

extern "C" void kernel_launch(void* const* d_in, const int* in_sizes, int n_in,
                              void* d_out, int out_size, void* d_ws, size_t ws_size,
                              hipStream_t stream) {
    const float* X   = (const float*)d_in[0];
    const float* ihw = (const float*)d_in[1];
    const float* ihb = (const float*)d_in[2];
    const float* hhw = (const float*)d_in[3];
    const float* hhb = (const float*)d_in[4];
    float* outp = (float*)d_out;
    float* wsp  = (float*)d_ws;

    hipFuncSetAttribute((const void*)rnn_persist,
                        hipFuncAttributeMaxDynamicSharedMemorySize,
                        SMEM_FLOATS * 4);

    // zero the h-state ping-pong buffers (re-done every call: replay-safe)
    hipMemsetAsync(d_ws, 0, (size_t)4 * Bb * Hh * sizeof(float), stream);

    void* args[] = {(void*)&X, (void*)&ihw, (void*)&ihb, (void*)&hhw,
                    (void*)&hhb, (void*)&outp, (void*)&wsp};
    hipLaunchCooperativeKernel((const void*)rnn_persist, dim3(NWG), dim3(NTHR),
                               args, (unsigned)(SMEM_FLOATS * 4), stream);
}

// Round 2
// 29468.027 us; speedup vs baseline: 2.4238x; 2.4238x over previous
//
#include <hip/hip_runtime.h>
#include <math.h>

#define Bb   8
#define Tt   2048
#define Hh   1024
#define NTHR 256
#define NWG  256
#define WPL  128          // workgroups per layer
#define CPW  8            // columns per workgroup
#define R0   4            // h0 ring slots (power of 2)
#define SUBC 4            // sub-counters per step (contention split)
#define CSTR 16           // dwords between sub-counters (64B lines)
#define CPT  (SUBC*CSTR)  // dwords of flag space per step per layer

// spin until the 4 sub-counters for one step sum to 128 (all WGs of a layer)
__device__ __forceinline__ void wait128(unsigned* base) {
    for (;;) {
        unsigned a = __hip_atomic_load(base +  0, __ATOMIC_RELAXED, __HIP_MEMORY_SCOPE_AGENT);
        unsigned b = __hip_atomic_load(base + 16, __ATOMIC_RELAXED, __HIP_MEMORY_SCOPE_AGENT);
        unsigned c = __hip_atomic_load(base + 32, __ATOMIC_RELAXED, __HIP_MEMORY_SCOPE_AGENT);
        unsigned d = __hip_atomic_load(base + 48, __ATOMIC_RELAXED, __HIP_MEMORY_SCOPE_AGENT);
        if ((a + b + c + d) == 128u) return;
        __builtin_amdgcn_s_sleep(1);
    }
}

__global__ __launch_bounds__(NTHR, 1)
void rnn_persist2(const float* __restrict__ X,
                  const float* __restrict__ ihw,
                  const float* __restrict__ ihb,
                  const float* __restrict__ hhw,
                  const float* __restrict__ hhb,
                  float* __restrict__ out,
                  float* __restrict__ ws)
{
    __shared__ float red[4*64];
    __shared__ float biasl[CPW];

    const int tid = threadIdx.x;
    const int wg  = blockIdx.x;
    const int lay = (wg >= WPL) ? 1 : 0;
    const int wgl = wg & (WPL-1);
    const int colbase = wgl * CPW;
    const int k0  = tid * 4;            // this thread's fixed k-slice
    const int sub = wgl & (SUBC-1);

    float* h0ring = ws;                              // [R0][Bb][Hh]
    float* h1ring = ws + (size_t)R0*Bb*Hh;           // [2][Bb][Hh]
    unsigned* c0  = (unsigned*)(ws + (size_t)(R0+2)*Bb*Hh);  // [Tt][CPT]
    unsigned* c1  = c0 + (size_t)Tt*CPT;

    // ---- persistent weights in registers: 8 cols x 4 k each for ih and hh ----
    float4 wA[CPW], wB[CPW];
    #pragma unroll
    for (int c = 0; c < CPW; ++c) {
        const int col = colbase + c;
        wA[c] = *(const float4*)&ihw[((size_t)lay*Hh + col)*Hh + k0];
        wB[c] = *(const float4*)&hhw[((size_t)lay*Hh + col)*Hh + k0];
    }
    if (tid < CPW) {
        const int col = colbase + tid;
        biasl[tid] = ihb[lay*Hh + col] + hhb[lay*Hh + col];
    }

    for (int t = 0; t < Tt; ++t) {
        // ---- prefetch X for this step (layer0 only; overlaps the spin) ----
        float4 av[Bb], bv[Bb];
        if (lay == 0) {
            #pragma unroll
            for (int b = 0; b < Bb; ++b)
                av[b] = *(const float4*)&X[((size_t)b*Tt + t)*Hh + k0];
        }

        // ---- dependency waits (thread 0 only) ----
        if (tid == 0) {
            if (lay == 0) {
                if (t > 0)   wait128(&c0[(size_t)(t-1)*CPT]);
                if (t >= R0) wait128(&c1[(size_t)(t-R0)*CPT]);   // ring WAR guard
            } else {
                wait128(&c0[(size_t)t*CPT]);
                if (t > 0)   wait128(&c1[(size_t)(t-1)*CPT]);
            }
            __builtin_amdgcn_fence(__ATOMIC_ACQUIRE, "agent");   // buffer_inv
        }
        __syncthreads();

        // ---- gather flag-dependent inputs (coalesced float4, registers only) ----
        if (lay == 0) {
            if (t > 0) {
                const float* hp = h0ring + (size_t)((t-1)&(R0-1))*Bb*Hh;
                #pragma unroll
                for (int b = 0; b < Bb; ++b)
                    bv[b] = *(const float4*)&hp[b*Hh + k0];
            } else {
                #pragma unroll
                for (int b = 0; b < Bb; ++b) bv[b] = make_float4(0.f,0.f,0.f,0.f);
            }
        } else {
            const float* ap = h0ring + (size_t)(t&(R0-1))*Bb*Hh;
            #pragma unroll
            for (int b = 0; b < Bb; ++b)
                av[b] = *(const float4*)&ap[b*Hh + k0];
            if (t > 0) {
                const float* hp = h1ring + (size_t)((t-1)&1)*Bb*Hh;
                #pragma unroll
                for (int b = 0; b < Bb; ++b)
                    bv[b] = *(const float4*)&hp[b*Hh + k0];
            } else {
                #pragma unroll
                for (int b = 0; b < Bb; ++b) bv[b] = make_float4(0.f,0.f,0.f,0.f);
            }
        }

        // ---- outer product: 8 cols x 8 batches x 8 k per thread ----
        float acc[CPW][Bb];
        #pragma unroll
        for (int c = 0; c < CPW; ++c)
            #pragma unroll
            for (int b = 0; b < Bb; ++b) acc[c][b] = 0.f;

        #pragma unroll
        for (int c = 0; c < CPW; ++c) {
            const float4 w0 = wA[c], w1 = wB[c];
            #pragma unroll
            for (int b = 0; b < Bb; ++b) {
                const float4 i0 = av[b], i1 = bv[b];
                acc[c][b] += w0.x*i0.x; acc[c][b] += w0.y*i0.y;
                acc[c][b] += w0.z*i0.z; acc[c][b] += w0.w*i0.w;
                acc[c][b] += w1.x*i1.x; acc[c][b] += w1.y*i1.y;
                acc[c][b] += w1.z*i1.z; acc[c][b] += w1.w*i1.w;
            }
        }

        // ---- intra-wave butterfly reduce: lane l ends with output o=l (o=b*8+c) ----
        float v[64];
        #pragma unroll
        for (int c = 0; c < CPW; ++c)
            #pragma unroll
            for (int b = 0; b < Bb; ++b) v[b*8 + c] = acc[c][b];
        const int lane = tid & 63;
        #pragma unroll
        for (int r = 0; r < 6; ++r) {
            const int bit = (lane >> r) & 1;
            #pragma unroll
            for (int j = 0; j < (64 >> (r + 1)); ++j) {
                const float send = bit ? v[2*j]     : v[2*j + 1];
                const float mine = bit ? v[2*j + 1] : v[2*j];
                const float recv = __shfl_xor(send, 1 << r, 64);
                v[j] = mine + recv;
            }
        }
        red[(tid >> 6)*64 + lane] = v[0];
        __syncthreads();

        // ---- combine 4 waves, bias, tanh, publish ----
        if (tid < 64) {
            const int b = tid >> 3, c = tid & 7;
            const int col = colbase + c;
            const float s = red[tid] + red[64 + tid] + red[128 + tid]
                          + red[192 + tid] + biasl[c];
            const float val = tanhf(s);
            if (lay == 0) {
                h0ring[(size_t)(t&(R0-1))*Bb*Hh + (size_t)b*Hh + col] = val;
                if (t == Tt-1)
                    out[(size_t)Bb*Tt*Hh + (size_t)b*Hh + col] = val;        // h_T[0]
            } else {
                h1ring[(size_t)(t&1)*Bb*Hh + (size_t)b*Hh + col] = val;
                out[((size_t)b*Tt + t)*Hh + col] = val;                      // ys
                if (t == Tt-1)
                    out[(size_t)Bb*Tt*Hh + (size_t)(Bb + b)*Hh + col] = val; // h_T[1]
            }
        }
        __syncthreads();   // all stores drained (vmcnt0 before barrier) -> in L2

        // ---- publish step-complete flag (RELEASE flushes L2 to coherence point) ----
        if (tid == 0) {
            unsigned* cc = (lay == 0) ? c0 : c1;
            __hip_atomic_fetch_add(&cc[(size_t)t*CPT + (size_t)sub*CSTR], 1u,
                                   __ATOMIC_RELEASE, __HIP_MEMORY_SCOPE_AGENT);
        }
    }
}

extern "C" void kernel_launch(void* const* d_in, const int* in_sizes, int n_in,
                              void* d_out, int out_size, void* d_ws, size_t ws_size,
                              hipStream_t stream) {
    const float* X   = (const float*)d_in[0];
    const float* ihw = (const float*)d_in[1];
    const float* ihb = (const float*)d_in[2];
    const float* hhw = (const float*)d_in[3];
    const float* hhb = (const float*)d_in[4];
    float* outp = (float*)d_out;
    float* wsp  = (float*)d_ws;

    // zero the per-step flag counters (rings need no init: t==0 skips reads)
    const size_t flag_off_bytes = (size_t)(R0+2)*Bb*Hh*sizeof(float);
    const size_t flag_bytes     = (size_t)2*Tt*CPT*sizeof(unsigned);
    hipMemsetAsync((char*)d_ws + flag_off_bytes, 0, flag_bytes, stream);

    hipLaunchKernelGGL(rnn_persist2, dim3(NWG), dim3(NTHR), 0, stream,
                       X, ihw, ihb, hhw, hhb, outp, wsp);
}

// Round 3
// 14225.932 us; speedup vs baseline: 5.0207x; 2.0714x over previous
//
#include <hip/hip_runtime.h>
#include <math.h>

typedef float f32x4 __attribute__((ext_vector_type(4)));

#define Bb   8
#define Tt   2048
#define Hh   1024
#define NTHR 256
#define NWG  256
#define WPL  128          // workgroups per layer
#define CPW  8            // columns per workgroup
#define R0   4            // h0 ring slots (power of 2)

// LLC-coherent access: sc0 sc1 = bypass L1+L2, read/write at the Infinity
// Cache (the chip-wide coherence point). No fences needed anywhere.
__device__ __forceinline__ void llc_load4(f32x4& dst, const float* p) {
    asm volatile("global_load_dwordx4 %0, %1, off sc0 sc1"
                 : "=v"(dst) : "v"(p));
}
__device__ __forceinline__ void llc_store1(float* p, float v) {
    asm volatile("global_store_dword %0, %1, off sc0 sc1"
                 :: "v"(p), "v"(v) : "memory");
}

__global__ __launch_bounds__(NTHR, 1)
void rnn_persist3(const float* __restrict__ X,
                  const float* __restrict__ ihw,
                  const float* __restrict__ ihb,
                  const float* __restrict__ hhw,
                  const float* __restrict__ hhb,
                  float* __restrict__ out,
                  float* __restrict__ ws)
{
    __shared__ float red[4*64];
    __shared__ float biasl[CPW];

    const int tid = threadIdx.x;
    const int wg  = blockIdx.x;
    const int lay = (wg >= WPL) ? 1 : 0;
    const int wgl = wg & (WPL-1);
    const int colbase = wgl * CPW;
    const int k0  = tid * 4;          // this thread's fixed k-slice

    float* h0ring = ws;                                      // [R0][Bb][Hh]
    float* h1ring = ws + (size_t)R0*Bb*Hh;                   // [2][Bb][Hh]
    unsigned* flags0 = (unsigned*)(ws + (size_t)(R0+2)*Bb*Hh); // [WPL]
    unsigned* flags1 = flags0 + WPL;                           // [WPL]
    unsigned long long* f0q = (unsigned long long*)flags0;
    unsigned long long* f1q = (unsigned long long*)flags1;
    unsigned* myflag = (lay ? flags1 : flags0) + wgl;

    // ---- persistent weights in registers: 8 cols x 4 k (ih and hh) ----
    f32x4 wA[CPW], wB[CPW];
    #pragma unroll
    for (int c = 0; c < CPW; ++c) {
        const int col = colbase + c;
        wA[c] = *(const f32x4*)&ihw[((size_t)lay*Hh + col)*Hh + k0];
        wB[c] = *(const f32x4*)&hhw[((size_t)lay*Hh + col)*Hh + k0];
    }
    if (tid < CPW) {
        const int col = colbase + tid;
        biasl[tid] = ihb[lay*Hh + col] + hhb[lay*Hh + col];
    }

    for (int t = 0; t < Tt; ++t) {
        f32x4 av[Bb], bv[Bb];
        // ---- X prefetch (layer0; plain cached loads, no dependency) ----
        if (lay == 0) {
            #pragma unroll
            for (int b = 0; b < Bb; ++b)
                av[b] = *(const f32x4*)&X[((size_t)b*Tt + t)*Hh + k0];
        }

        // ---- dependency wait: per-WG monotonic flags, wave0 polls ----
        // l0[t]: all l0 done t-1 (flags0>=t), ring WAR: all l1 done t-3 (flags1>=t-3)
        // l1[t]: all l0 done t (flags0>=t+1), all l1 done t-1 (flags1>=t)
        const int tA = lay ? (t + 1) : t;
        const int tB = lay ? t : (t - (R0 - 1));
        if ((tA > 0) | (tB > 0)) {
            if (tid < 64) {
                const unsigned uA = tA > 0 ? (unsigned)tA : 0u;
                const unsigned uB = tB > 0 ? (unsigned)tB : 0u;
                for (;;) {
                    unsigned long long a = __hip_atomic_load(&f0q[tid],
                        __ATOMIC_RELAXED, __HIP_MEMORY_SCOPE_AGENT);
                    unsigned long long b = __hip_atomic_load(&f1q[tid],
                        __ATOMIC_RELAXED, __HIP_MEMORY_SCOPE_AGENT);
                    const bool ok = ((unsigned)a >= uA) & ((unsigned)(a >> 32) >= uA)
                                  & ((unsigned)b >= uB) & ((unsigned)(b >> 32) >= uB);
                    if (__all(ok)) break;
                    __builtin_amdgcn_s_sleep(1);
                }
            }
        }
        __syncthreads();

        // ---- gather flag-dependent inputs straight from LLC ----
        {
            const float* bp0 = h0ring + (size_t)((t-1)&(R0-1))*Bb*Hh; // l0: h0(t-1)
            const float* ap1 = h0ring + (size_t)( t   &(R0-1))*Bb*Hh; // l1: h0(t)
            const float* bp1 = h1ring + (size_t)((t-1)&1)*Bb*Hh;      // l1: h1(t-1)
            if (lay == 0) {
                #pragma unroll
                for (int b = 0; b < Bb; ++b) llc_load4(bv[b], bp0 + (size_t)b*Hh + k0);
            } else {
                #pragma unroll
                for (int b = 0; b < Bb; ++b) llc_load4(av[b], ap1 + (size_t)b*Hh + k0);
                #pragma unroll
                for (int b = 0; b < Bb; ++b) llc_load4(bv[b], bp1 + (size_t)b*Hh + k0);
            }
        }
        asm volatile("s_waitcnt vmcnt(0)" ::: "memory");
        __builtin_amdgcn_sched_barrier(0);   // keep uses after the waitcnt

        // ---- outer product: 8 cols x 8 batches x 8 k per thread ----
        float acc[CPW][Bb];
        #pragma unroll
        for (int c = 0; c < CPW; ++c)
            #pragma unroll
            for (int b = 0; b < Bb; ++b) acc[c][b] = 0.f;

        #pragma unroll
        for (int c = 0; c < CPW; ++c) {
            const f32x4 w0 = wA[c], w1 = wB[c];
            #pragma unroll
            for (int b = 0; b < Bb; ++b) {
                const f32x4 i0 = av[b], i1 = bv[b];
                #pragma unroll
                for (int j = 0; j < 4; ++j) {
                    acc[c][b] += w0[j]*i0[j];
                    acc[c][b] += w1[j]*i1[j];
                }
            }
        }

        // ---- intra-wave butterfly reduce: lane l ends with output o=l (o=b*8+c) ----
        float v[64];
        #pragma unroll
        for (int c = 0; c < CPW; ++c)
            #pragma unroll
            for (int b = 0; b < Bb; ++b) v[b*8 + c] = acc[c][b];
        const int lane = tid & 63;
        #pragma unroll
        for (int r = 0; r < 6; ++r) {
            const int bit = (lane >> r) & 1;
            #pragma unroll
            for (int j = 0; j < (64 >> (r + 1)); ++j) {
                const float send = bit ? v[2*j]     : v[2*j + 1];
                const float mine = bit ? v[2*j + 1] : v[2*j];
                const float recv = __shfl_xor(send, 1 << r, 64);
                v[j] = mine + recv;
            }
        }
        red[(tid >> 6)*64 + lane] = v[0];
        __syncthreads();

        // ---- combine 4 waves, bias, tanh, publish (wave0 only) ----
        if (tid < 64) {
            const int b = tid >> 3, c = tid & 7;
            const int col = colbase + c;
            const float s = red[tid] + red[64 + tid] + red[128 + tid]
                          + red[192 + tid] + biasl[c];
            const float val = tanhf(s);
            if (lay == 0) {
                llc_store1(h0ring + (size_t)(t&(R0-1))*Bb*Hh + (size_t)b*Hh + col, val);
                if (t == Tt-1)
                    out[(size_t)Bb*Tt*Hh + (size_t)b*Hh + col] = val;        // h_T[0]
            } else {
                llc_store1(h1ring + (size_t)(t&1)*Bb*Hh + (size_t)b*Hh + col, val);
                out[((size_t)b*Tt + t)*Hh + col] = val;                      // ys
                if (t == Tt-1)
                    out[(size_t)Bb*Tt*Hh + (size_t)(Bb + b)*Hh + col] = val; // h_T[1]
            }
            // data at LLC before flag: vmcnt(0) then plain-relaxed flag store
            asm volatile("s_waitcnt vmcnt(0)" ::: "memory");
            if (tid == 0)
                __hip_atomic_store(myflag, (unsigned)(t + 1),
                                   __ATOMIC_RELAXED, __HIP_MEMORY_SCOPE_AGENT);
        }
    }
}

extern "C" void kernel_launch(void* const* d_in, const int* in_sizes, int n_in,
                              void* d_out, int out_size, void* d_ws, size_t ws_size,
                              hipStream_t stream) {
    const float* X   = (const float*)d_in[0];
    const float* ihw = (const float*)d_in[1];
    const float* ihb = (const float*)d_in[2];
    const float* hhw = (const float*)d_in[3];
    const float* hhb = (const float*)d_in[4];
    float* outp = (float*)d_out;
    float* wsp  = (float*)d_ws;

    // zero h rings (t==0 reads them) and the per-WG flags; replay-safe
    const size_t zero_bytes = (size_t)(R0+2)*Bb*Hh*sizeof(float)
                            + (size_t)2*WPL*sizeof(unsigned);
    hipMemsetAsync(d_ws, 0, zero_bytes, stream);

    hipLaunchKernelGGL(rnn_persist3, dim3(NWG), dim3(NTHR), 0, stream,
                       X, ihw, ihb, hhw, hhb, outp, wsp);
}

// Round 5
// 10856.896 us; speedup vs baseline: 6.5787x; 1.3103x over previous
//
#include <hip/hip_runtime.h>
#include <math.h>

typedef float f32x4 __attribute__((ext_vector_type(4)));

#define Bb   8
#define Tt   2048
#define Hh   1024
#define NTHR 256
#define NWG  256
#define WPL  128          // workgroups per layer
#define CPW  8            // columns per workgroup
#define R0   4            // h0 ring slots (power of 2)

// LLC-coherent ops: sc0 sc1 = bypass L1+L2, hit the Infinity Cache (chip-wide
// coherence point). Ordering via explicit vmcnt only. (Proven in round 3.)
__device__ __forceinline__ void llc_load4(f32x4& d, const float* p) {
    asm volatile("global_load_dwordx4 %0, %1, off sc0 sc1" : "=v"(d) : "v"(p));
}
__device__ __forceinline__ void llc_store1(float* p, float v) {
    asm volatile("global_store_dword %0, %1, off sc0 sc1" :: "v"(p), "v"(v) : "memory");
}
__device__ __forceinline__ void vm0() {
    asm volatile("s_waitcnt vmcnt(0)" ::: "memory");
    __builtin_amdgcn_sched_barrier(0);   // rule #18: pin consumers after the wait
}
__device__ __forceinline__ float fast_tanh(float s) {
    const float e = __expf(2.f * s);
    return 1.f - 2.f / (e + 1.f);
}

// lanes 0..63 each watch 2 counters of fq[64]; returns when all 128 >= u.
// Round-3-proven poll: relaxed agent atomic loads + s_sleep backoff.
__device__ __forceinline__ void wait_ge(const unsigned long long* fq, int tid, unsigned u) {
    unsigned long long a = __hip_atomic_load(fq + tid, __ATOMIC_RELAXED,
                                             __HIP_MEMORY_SCOPE_AGENT);
    bool ok = ((unsigned)a >= u) & ((unsigned)(a >> 32) >= u);
    while (!__all(ok)) {
        __builtin_amdgcn_s_sleep(1);
        a = __hip_atomic_load(fq + tid, __ATOMIC_RELAXED, __HIP_MEMORY_SCOPE_AGENT);
        ok = ((unsigned)a >= u) & ((unsigned)(a >> 32) >= u);
    }
}

__global__ __launch_bounds__(NTHR, 1)
void rnn_persist5(const float* __restrict__ X,
                  const float* __restrict__ ihw,
                  const float* __restrict__ ihb,
                  const float* __restrict__ hhw,
                  const float* __restrict__ hhb,
                  float* __restrict__ out,
                  float* __restrict__ ws)
{
    __shared__ float red[4*64];
    __shared__ float biasl[CPW];

    const int tid = threadIdx.x;
    const int wg  = blockIdx.x;
    const int lay = (wg >= WPL) ? 1 : 0;
    const int wgl = wg & (WPL-1);
    const int colbase = wgl * CPW;
    const int k0  = tid * 4;
    const int lane = tid & 63;

    float* h0ring = ws;                                        // [R0][Bb][Hh]
    float* h1ring = ws + (size_t)R0*Bb*Hh;                     // [2][Bb][Hh]
    unsigned* flags0 = (unsigned*)(ws + (size_t)(R0+2)*Bb*Hh); // [WPL]
    unsigned* flags1 = flags0 + WPL;
    const unsigned long long* f0q = (const unsigned long long*)flags0;
    const unsigned long long* f1q = (const unsigned long long*)flags1;
    unsigned* myflag = (lay ? flags1 : flags0) + wgl;

    // persistent weights in registers: 8 cols x 4 k (ih and hh)
    f32x4 wA[CPW], wB[CPW];
    #pragma unroll
    for (int c = 0; c < CPW; ++c) {
        const int col = colbase + c;
        wA[c] = *(const f32x4*)&ihw[((size_t)lay*Hh + col)*Hh + k0];
        wB[c] = *(const f32x4*)&hhw[((size_t)lay*Hh + col)*Hh + k0];
    }
    if (tid < CPW) {
        const int col = colbase + tid;
        biasl[tid] = ihb[lay*Hh + col] + hhb[lay*Hh + col];
    }
    __syncthreads();

    if (lay == 0) {
        // ---------------- layer 0 ----------------
        f32x4 xc[Bb];                      // X(t) pipelined in regs
        #pragma unroll
        for (int b = 0; b < Bb; ++b)
            xc[b] = *(const f32x4*)&X[((size_t)b*Tt + 0)*Hh + k0];

        for (int t = 0; t < Tt; ++t) {
            // 1) ih partials BEFORE the wait (hides publish->observe RT)
            float acc[CPW][Bb];
            #pragma unroll
            for (int c = 0; c < CPW; ++c) {
                const f32x4 w0 = wA[c];
                #pragma unroll
                for (int b = 0; b < Bb; ++b) {
                    const f32x4 i0 = xc[b];
                    float a = w0[0]*i0[0]; a += w0[1]*i0[1];
                    a += w0[2]*i0[2]; a += w0[3]*i0[3];
                    acc[c][b] = a;
                }
            }

            // 2) wait: peers done t-1; ring WAR: l1 done t-R0
            if (tid < 64 && t > 0) {
                wait_ge(f0q, tid, (unsigned)t);
                const int tB = t - (R0 - 1);
                if (tB > 0) wait_ge(f1q, tid, (unsigned)tB);
            }
            __syncthreads();

            // 3) hh half (the only flag-dependent compute)
            if (t > 0) {
                const float* hp = h0ring + (size_t)((t-1)&(R0-1))*Bb*Hh;
                f32x4 hv[Bb];
                #pragma unroll
                for (int b = 0; b < Bb; ++b) llc_load4(hv[b], hp + (size_t)b*Hh + k0);
                vm0();
                #pragma unroll
                for (int c = 0; c < CPW; ++c) {
                    const f32x4 w1 = wB[c];
                    #pragma unroll
                    for (int b = 0; b < Bb; ++b) {
                        const f32x4 i1 = hv[b];
                        acc[c][b] += w1[0]*i1[0]; acc[c][b] += w1[1]*i1[1];
                        acc[c][b] += w1[2]*i1[2]; acc[c][b] += w1[3]*i1[3];
                    }
                }
            }

            // 4) butterfly: lane ends with output o = lane (o = b*8 + c)
            float v[64];
            #pragma unroll
            for (int c = 0; c < CPW; ++c)
                #pragma unroll
                for (int b = 0; b < Bb; ++b) v[b*8 + c] = acc[c][b];
            #pragma unroll
            for (int r = 0; r < 6; ++r) {
                const int bit = (lane >> r) & 1;
                #pragma unroll
                for (int j = 0; j < (64 >> (r + 1)); ++j) {
                    const float send = bit ? v[2*j]     : v[2*j + 1];
                    const float mine = bit ? v[2*j + 1] : v[2*j];
                    v[j] = mine + __shfl_xor(send, 1 << r, 64);
                }
            }
            red[(tid >> 6)*64 + lane] = v[0];
            __syncthreads();

            // 5) combine + tanh + publish-first epilogue
            if (tid < 64) {
                const int b = tid >> 3, c = tid & 7;
                const float s = red[tid] + red[64 + tid] + red[128 + tid]
                              + red[192 + tid] + biasl[c];
                const float val = fast_tanh(s);
                llc_store1(h0ring + (size_t)(t&(R0-1))*Bb*Hh + (size_t)b*Hh
                           + colbase + c, val);
                asm volatile("s_waitcnt vmcnt(0)" ::: "memory");
                if (tid == 0)
                    __hip_atomic_store(myflag, (unsigned)(t + 1),
                                       __ATOMIC_RELAXED, __HIP_MEMORY_SCOPE_AGENT);
                if (t == Tt-1)
                    out[(size_t)Bb*Tt*Hh + (size_t)b*Hh + colbase + c] = val; // h_T[0]
            }

            // 6) X prefetch for t+1 (off critical path)
            const int tn = (t + 1 < Tt) ? (t + 1) : t;
            #pragma unroll
            for (int b = 0; b < Bb; ++b)
                xc[b] = *(const f32x4*)&X[((size_t)b*Tt + tn)*Hh + k0];
        }
    } else {
        // ---------------- layer 1 ----------------
        for (int t = 0; t < Tt; ++t) {
            float acc[CPW][Bb];
            #pragma unroll
            for (int c = 0; c < CPW; ++c)
                #pragma unroll
                for (int b = 0; b < Bb; ++b) acc[c][b] = 0.f;

            // stage 1: h1(t-1) ready (usually already satisfied) -> hh half
            if (t > 0) {
                if (tid < 64) wait_ge(f1q, tid, (unsigned)t);
                __syncthreads();
                const float* hp = h1ring + (size_t)((t-1)&1)*Bb*Hh;
                f32x4 hv[Bb];
                #pragma unroll
                for (int b = 0; b < Bb; ++b) llc_load4(hv[b], hp + (size_t)b*Hh + k0);
                vm0();
                #pragma unroll
                for (int c = 0; c < CPW; ++c) {
                    const f32x4 w1 = wB[c];
                    #pragma unroll
                    for (int b = 0; b < Bb; ++b) {
                        const f32x4 i1 = hv[b];
                        acc[c][b] += w1[0]*i1[0]; acc[c][b] += w1[1]*i1[1];
                        acc[c][b] += w1[2]*i1[2]; acc[c][b] += w1[3]*i1[3];
                    }
                }
            }

            // stage 2: h0(t) ready -> ih half
            if (tid < 64) wait_ge(f0q, tid, (unsigned)(t + 1));
            __syncthreads();
            {
                const float* ap = h0ring + (size_t)(t&(R0-1))*Bb*Hh;
                f32x4 av[Bb];
                #pragma unroll
                for (int b = 0; b < Bb; ++b) llc_load4(av[b], ap + (size_t)b*Hh + k0);
                vm0();
                #pragma unroll
                for (int c = 0; c < CPW; ++c) {
                    const f32x4 w0 = wA[c];
                    #pragma unroll
                    for (int b = 0; b < Bb; ++b) {
                        const f32x4 i0 = av[b];
                        acc[c][b] += w0[0]*i0[0]; acc[c][b] += w0[1]*i0[1];
                        acc[c][b] += w0[2]*i0[2]; acc[c][b] += w0[3]*i0[3];
                    }
                }
            }

            // butterfly
            float v[64];
            #pragma unroll
            for (int c = 0; c < CPW; ++c)
                #pragma unroll
                for (int b = 0; b < Bb; ++b) v[b*8 + c] = acc[c][b];
            #pragma unroll
            for (int r = 0; r < 6; ++r) {
                const int bit = (lane >> r) & 1;
                #pragma unroll
                for (int j = 0; j < (64 >> (r + 1)); ++j) {
                    const float send = bit ? v[2*j]     : v[2*j + 1];
                    const float mine = bit ? v[2*j + 1] : v[2*j];
                    v[j] = mine + __shfl_xor(send, 1 << r, 64);
                }
            }
            red[(tid >> 6)*64 + lane] = v[0];
            __syncthreads();

            // combine + tanh + publish-first epilogue; ys/h_T after the flag
            if (tid < 64) {
                const int b = tid >> 3, c = tid & 7;
                const float s = red[tid] + red[64 + tid] + red[128 + tid]
                              + red[192 + tid] + biasl[c];
                const float val = fast_tanh(s);
                llc_store1(h1ring + (size_t)(t&1)*Bb*Hh + (size_t)b*Hh
                           + colbase + c, val);
                asm volatile("s_waitcnt vmcnt(0)" ::: "memory");
                if (tid == 0)
                    __hip_atomic_store(myflag, (unsigned)(t + 1),
                                       __ATOMIC_RELAXED, __HIP_MEMORY_SCOPE_AGENT);
                out[((size_t)b*Tt + t)*Hh + colbase + c] = val;              // ys
                if (t == Tt-1)
                    out[(size_t)Bb*Tt*Hh + (size_t)(Bb + b)*Hh + colbase + c] = val; // h_T[1]
            }
        }
    }
}

extern "C" void kernel_launch(void* const* d_in, const int* in_sizes, int n_in,
                              void* d_out, int out_size, void* d_ws, size_t ws_size,
                              hipStream_t stream) {
    const float* X   = (const float*)d_in[0];
    const float* ihw = (const float*)d_in[1];
    const float* ihb = (const float*)d_in[2];
    const float* hhw = (const float*)d_in[3];
    const float* hhb = (const float*)d_in[4];
    float* outp = (float*)d_out;
    float* wsp  = (float*)d_ws;

    // zero h rings (t==0 reads them) and per-WG flags; replay-safe
    const size_t zero_bytes = (size_t)(R0+2)*Bb*Hh*sizeof(float)
                            + (size_t)2*WPL*sizeof(unsigned);
    hipMemsetAsync(d_ws, 0, zero_bytes, stream);

    hipLaunchKernelGGL(rnn_persist5, dim3(NWG), dim3(NTHR), 0, stream,
                       X, ihw, ihb, hhw, hhb, outp, wsp);
}

// Round 6
// 10553.357 us; speedup vs baseline: 6.7679x; 1.0288x over previous
//
#include <hip/hip_runtime.h>
#include <math.h>

typedef float f32x4 __attribute__((ext_vector_type(4)));

#define Bb   8
#define Tt   2048
#define Hh   1024
#define NTHR 256
#define NWG  256
#define WPL  128          // workgroups per layer
#define CPW  8            // columns per workgroup
#define R0   4            // fallback ring slots

// ---- cache-control primitives (semantics proven in rounds 3/5) ----
// sc0 sc1 : bypass L1+L2, read/write at the Infinity Cache (coherence point)
// sc0     : bypass L1 only; L2-cacheable (safe for write-once data)
__device__ __forceinline__ void llc_load4(f32x4& d, const float* p) {
    asm volatile("global_load_dwordx4 %0, %1, off sc0 sc1" : "=v"(d) : "v"(p));
}
__device__ __forceinline__ void l2_load4(f32x4& d, const float* p) {
    asm volatile("global_load_dwordx4 %0, %1, off sc0" : "=v"(d) : "v"(p));
}
__device__ __forceinline__ void wt_store1(float* p, float v) {   // write-through
    asm volatile("global_store_dword %0, %1, off sc0 sc1" :: "v"(p), "v"(v) : "memory");
}
__device__ __forceinline__ void vm0() {
    asm volatile("s_waitcnt vmcnt(0)" ::: "memory");
    __builtin_amdgcn_sched_barrier(0);   // rule #18: pin consumers after the wait
}
__device__ __forceinline__ float fast_tanh(float s) {
    const float e = __expf(2.f * s);
    return 1.f - 2.f / (e + 1.f);
}
// lanes 0..63 watch 2 counters each of fq[64]; return when all 128 >= u.
__device__ __forceinline__ void wait_ge(const unsigned long long* fq, int tid, unsigned u) {
    unsigned long long a = __hip_atomic_load(fq + tid, __ATOMIC_RELAXED,
                                             __HIP_MEMORY_SCOPE_AGENT);
    bool ok = ((unsigned)a >= u) & ((unsigned)(a >> 32) >= u);
    while (!__all(ok)) {
        __builtin_amdgcn_s_sleep(1);
        a = __hip_atomic_load(fq + tid, __ATOMIC_RELAXED, __HIP_MEMORY_SCOPE_AGENT);
        ok = ((unsigned)a >= u) & ((unsigned)(a >> 32) >= u);
    }
}

#define BUTTERFLY()                                                        \
    do {                                                                   \
        _Pragma("unroll")                                                  \
        for (int r = 0; r < 6; ++r) {                                      \
            const int bit = (lane >> r) & 1;                               \
            _Pragma("unroll")                                              \
            for (int j = 0; j < (64 >> (r + 1)); ++j) {                    \
                const float send = bit ? v[2*j]     : v[2*j + 1];          \
                const float mine = bit ? v[2*j + 1] : v[2*j];              \
                v[j] = mine + __shfl_xor(send, 1 << r, 64);                \
            }                                                              \
        }                                                                  \
    } while (0)

// =====================  primary: write-once history  =====================
__global__ __launch_bounds__(NTHR, 1)
void rnn_hist(const float* __restrict__ X,
              const float* __restrict__ ihw,
              const float* __restrict__ ihb,
              const float* __restrict__ hhw,
              const float* __restrict__ hhb,
              float* __restrict__ out,
              float* __restrict__ ws)
{
    __shared__ float red[4*64];
    __shared__ float biasl[CPW];

    // flush poison / prior-replay lines from this XCD's L1+L2 once per run;
    // after this, write-once data can never be stale in local caches.
    __builtin_amdgcn_fence(__ATOMIC_ACQUIRE, "agent");

    const int tid = threadIdx.x;
    const int wg  = blockIdx.x;
    const int lay = (wg >= WPL) ? 1 : 0;
    const int wgl = wg & (WPL-1);
    const int colbase = wgl * CPW;
    const int k0  = tid * 4;
    const int lane = tid & 63;

    float* h0hist = ws;                                   // [Tt][Bb][Hh]
    unsigned* flags0 = (unsigned*)(ws + (size_t)Tt*Bb*Hh); // [WPL]
    unsigned* flags1 = flags0 + WPL;
    const unsigned long long* f0q = (const unsigned long long*)flags0;
    const unsigned long long* f1q = (const unsigned long long*)flags1;
    unsigned* myflag = (lay ? flags1 : flags0) + wgl;

    // persistent weights in registers: 8 cols x 4 k (ih and hh)
    f32x4 wA[CPW], wB[CPW];
    #pragma unroll
    for (int c = 0; c < CPW; ++c) {
        const int col = colbase + c;
        wA[c] = *(const f32x4*)&ihw[((size_t)lay*Hh + col)*Hh + k0];
        wB[c] = *(const f32x4*)&hhw[((size_t)lay*Hh + col)*Hh + k0];
    }
    if (tid < CPW) {
        const int col = colbase + tid;
        biasl[tid] = ihb[lay*Hh + col] + hhb[lay*Hh + col];
    }
    __syncthreads();

    if (lay == 0) {
        // ---------------- layer 0 ----------------
        f32x4 xc[Bb];
        #pragma unroll
        for (int b = 0; b < Bb; ++b)
            xc[b] = *(const f32x4*)&X[((size_t)b*Tt + 0)*Hh + k0];

        for (int t = 0; t < Tt; ++t) {
            // 1) ih partials BEFORE the wait (hides publish->observe RT)
            float acc[CPW][Bb];
            #pragma unroll
            for (int c = 0; c < CPW; ++c) {
                const f32x4 w0 = wA[c];
                #pragma unroll
                for (int b = 0; b < Bb; ++b) {
                    const f32x4 i0 = xc[b];
                    float a = w0[0]*i0[0]; a += w0[1]*i0[1];
                    a += w0[2]*i0[2]; a += w0[3]*i0[3];
                    acc[c][b] = a;
                }
            }

            // 2) wait: peers done t-1 (no WAR wait — history, no reuse)
            if (tid < 64 && t > 0) wait_ge(f0q, tid, (unsigned)t);
            __syncthreads();

            // 3) hh half — h0(t-1) via L2-cacheable loads (write-once data)
            if (t > 0) {
                const float* hp = h0hist + (size_t)(t-1)*Bb*Hh;
                f32x4 hv[Bb];
                #pragma unroll
                for (int b = 0; b < Bb; ++b) l2_load4(hv[b], hp + (size_t)b*Hh + k0);
                vm0();
                #pragma unroll
                for (int c = 0; c < CPW; ++c) {
                    const f32x4 w1 = wB[c];
                    #pragma unroll
                    for (int b = 0; b < Bb; ++b) {
                        const f32x4 i1 = hv[b];
                        acc[c][b] += w1[0]*i1[0]; acc[c][b] += w1[1]*i1[1];
                        acc[c][b] += w1[2]*i1[2]; acc[c][b] += w1[3]*i1[3];
                    }
                }
            }

            // 4) butterfly: lane ends with output o = lane (o = b*8 + c)
            float v[64];
            #pragma unroll
            for (int c = 0; c < CPW; ++c)
                #pragma unroll
                for (int b = 0; b < Bb; ++b) v[b*8 + c] = acc[c][b];
            BUTTERFLY();
            red[(tid >> 6)*64 + lane] = v[0];
            __syncthreads();

            // 5) combine + tanh + publish-first epilogue
            if (tid < 64) {
                const int b = tid >> 3, c = tid & 7;
                const float s = red[tid] + red[64 + tid] + red[128 + tid]
                              + red[192 + tid] + biasl[c];
                const float val = fast_tanh(s);
                wt_store1(h0hist + (size_t)t*Bb*Hh + (size_t)b*Hh + colbase + c, val);
                asm volatile("s_waitcnt vmcnt(0)" ::: "memory");
                if (tid == 0)
                    __hip_atomic_store(myflag, (unsigned)(t + 1),
                                       __ATOMIC_RELAXED, __HIP_MEMORY_SCOPE_AGENT);
                if (t == Tt-1)
                    out[(size_t)Bb*Tt*Hh + (size_t)b*Hh + colbase + c] = val; // h_T[0]
            }

            // 6) X prefetch for t+1 (off critical path)
            const int tn = (t + 1 < Tt) ? (t + 1) : t;
            #pragma unroll
            for (int b = 0; b < Bb; ++b)
                xc[b] = *(const f32x4*)&X[((size_t)b*Tt + tn)*Hh + k0];
        }
    } else {
        // ---------------- layer 1 (h1 history IS ys in d_out) ----------------
        for (int t = 0; t < Tt; ++t) {
            float acc[CPW][Bb];
            #pragma unroll
            for (int c = 0; c < CPW; ++c)
                #pragma unroll
                for (int b = 0; b < Bb; ++b) acc[c][b] = 0.f;

            // stage 1: h1(t-1) ready -> hh half (read from out, L2-cacheable)
            if (t > 0) {
                if (tid < 64) wait_ge(f1q, tid, (unsigned)t);
                __syncthreads();
                f32x4 hv[Bb];
                #pragma unroll
                for (int b = 0; b < Bb; ++b)
                    l2_load4(hv[b], out + ((size_t)b*Tt + (t-1))*Hh + k0);
                vm0();
                #pragma unroll
                for (int c = 0; c < CPW; ++c) {
                    const f32x4 w1 = wB[c];
                    #pragma unroll
                    for (int b = 0; b < Bb; ++b) {
                        const f32x4 i1 = hv[b];
                        acc[c][b] += w1[0]*i1[0]; acc[c][b] += w1[1]*i1[1];
                        acc[c][b] += w1[2]*i1[2]; acc[c][b] += w1[3]*i1[3];
                    }
                }
            }

            // stage 2: h0(t) ready -> ih half
            if (tid < 64) wait_ge(f0q, tid, (unsigned)(t + 1));
            __syncthreads();
            {
                const float* ap = h0hist + (size_t)t*Bb*Hh;
                f32x4 av[Bb];
                #pragma unroll
                for (int b = 0; b < Bb; ++b) l2_load4(av[b], ap + (size_t)b*Hh + k0);
                vm0();
                #pragma unroll
                for (int c = 0; c < CPW; ++c) {
                    const f32x4 w0 = wA[c];
                    #pragma unroll
                    for (int b = 0; b < Bb; ++b) {
                        const f32x4 i0 = av[b];
                        acc[c][b] += w0[0]*i0[0]; acc[c][b] += w0[1]*i0[1];
                        acc[c][b] += w0[2]*i0[2]; acc[c][b] += w0[3]*i0[3];
                    }
                }
            }

            // butterfly
            float v[64];
            #pragma unroll
            for (int c = 0; c < CPW; ++c)
                #pragma unroll
                for (int b = 0; b < Bb; ++b) v[b*8 + c] = acc[c][b];
            BUTTERFLY();
            red[(tid >> 6)*64 + lane] = v[0];
            __syncthreads();

            // combine + tanh; ys store IS the h1 publish data (write-through)
            if (tid < 64) {
                const int b = tid >> 3, c = tid & 7;
                const float s = red[tid] + red[64 + tid] + red[128 + tid]
                              + red[192 + tid] + biasl[c];
                const float val = fast_tanh(s);
                wt_store1(out + ((size_t)b*Tt + t)*Hh + colbase + c, val);
                asm volatile("s_waitcnt vmcnt(0)" ::: "memory");
                if (tid == 0)
                    __hip_atomic_store(myflag, (unsigned)(t + 1),
                                       __ATOMIC_RELAXED, __HIP_MEMORY_SCOPE_AGENT);
                if (t == Tt-1)
                    out[(size_t)Bb*Tt*Hh + (size_t)(Bb + b)*Hh + colbase + c] = val; // h_T[1]
            }
        }
    }
}

// =====================  fallback: round-5 ring kernel (proven)  ==========
__global__ __launch_bounds__(NTHR, 1)
void rnn_persist5(const float* __restrict__ X,
                  const float* __restrict__ ihw,
                  const float* __restrict__ ihb,
                  const float* __restrict__ hhw,
                  const float* __restrict__ hhb,
                  float* __restrict__ out,
                  float* __restrict__ ws)
{
    __shared__ float red[4*64];
    __shared__ float biasl[CPW];
    const int tid = threadIdx.x;
    const int wg  = blockIdx.x;
    const int lay = (wg >= WPL) ? 1 : 0;
    const int wgl = wg & (WPL-1);
    const int colbase = wgl * CPW;
    const int k0  = tid * 4;
    const int lane = tid & 63;

    float* h0ring = ws;
    float* h1ring = ws + (size_t)R0*Bb*Hh;
    unsigned* flags0 = (unsigned*)(ws + (size_t)(R0+2)*Bb*Hh);
    unsigned* flags1 = flags0 + WPL;
    const unsigned long long* f0q = (const unsigned long long*)flags0;
    const unsigned long long* f1q = (const unsigned long long*)flags1;
    unsigned* myflag = (lay ? flags1 : flags0) + wgl;

    f32x4 wA[CPW], wB[CPW];
    #pragma unroll
    for (int c = 0; c < CPW; ++c) {
        const int col = colbase + c;
        wA[c] = *(const f32x4*)&ihw[((size_t)lay*Hh + col)*Hh + k0];
        wB[c] = *(const f32x4*)&hhw[((size_t)lay*Hh + col)*Hh + k0];
    }
    if (tid < CPW) {
        const int col = colbase + tid;
        biasl[tid] = ihb[lay*Hh + col] + hhb[lay*Hh + col];
    }
    __syncthreads();

    if (lay == 0) {
        f32x4 xc[Bb];
        #pragma unroll
        for (int b = 0; b < Bb; ++b)
            xc[b] = *(const f32x4*)&X[((size_t)b*Tt + 0)*Hh + k0];
        for (int t = 0; t < Tt; ++t) {
            float acc[CPW][Bb];
            #pragma unroll
            for (int c = 0; c < CPW; ++c) {
                const f32x4 w0 = wA[c];
                #pragma unroll
                for (int b = 0; b < Bb; ++b) {
                    const f32x4 i0 = xc[b];
                    float a = w0[0]*i0[0]; a += w0[1]*i0[1];
                    a += w0[2]*i0[2]; a += w0[3]*i0[3];
                    acc[c][b] = a;
                }
            }
            if (tid < 64 && t > 0) {
                wait_ge(f0q, tid, (unsigned)t);
                const int tB = t - (R0 - 1);
                if (tB > 0) wait_ge(f1q, tid, (unsigned)tB);
            }
            __syncthreads();
            if (t > 0) {
                const float* hp = h0ring + (size_t)((t-1)&(R0-1))*Bb*Hh;
                f32x4 hv[Bb];
                #pragma unroll
                for (int b = 0; b < Bb; ++b) llc_load4(hv[b], hp + (size_t)b*Hh + k0);
                vm0();
                #pragma unroll
                for (int c = 0; c < CPW; ++c) {
                    const f32x4 w1 = wB[c];
                    #pragma unroll
                    for (int b = 0; b < Bb; ++b) {
                        const f32x4 i1 = hv[b];
                        acc[c][b] += w1[0]*i1[0]; acc[c][b] += w1[1]*i1[1];
                        acc[c][b] += w1[2]*i1[2]; acc[c][b] += w1[3]*i1[3];
                    }
                }
            }
            float v[64];
            #pragma unroll
            for (int c = 0; c < CPW; ++c)
                #pragma unroll
                for (int b = 0; b < Bb; ++b) v[b*8 + c] = acc[c][b];
            BUTTERFLY();
            red[(tid >> 6)*64 + lane] = v[0];
            __syncthreads();
            if (tid < 64) {
                const int b = tid >> 3, c = tid & 7;
                const float s = red[tid] + red[64 + tid] + red[128 + tid]
                              + red[192 + tid] + biasl[c];
                const float val = fast_tanh(s);
                wt_store1(h0ring + (size_t)(t&(R0-1))*Bb*Hh + (size_t)b*Hh
                          + colbase + c, val);
                asm volatile("s_waitcnt vmcnt(0)" ::: "memory");
                if (tid == 0)
                    __hip_atomic_store(myflag, (unsigned)(t + 1),
                                       __ATOMIC_RELAXED, __HIP_MEMORY_SCOPE_AGENT);
                if (t == Tt-1)
                    out[(size_t)Bb*Tt*Hh + (size_t)b*Hh + colbase + c] = val;
            }
            const int tn = (t + 1 < Tt) ? (t + 1) : t;
            #pragma unroll
            for (int b = 0; b < Bb; ++b)
                xc[b] = *(const f32x4*)&X[((size_t)b*Tt + tn)*Hh + k0];
        }
    } else {
        for (int t = 0; t < Tt; ++t) {
            float acc[CPW][Bb];
            #pragma unroll
            for (int c = 0; c < CPW; ++c)
                #pragma unroll
                for (int b = 0; b < Bb; ++b) acc[c][b] = 0.f;
            if (t > 0) {
                if (tid < 64) wait_ge(f1q, tid, (unsigned)t);
                __syncthreads();
                const float* hp = h1ring + (size_t)((t-1)&1)*Bb*Hh;
                f32x4 hv[Bb];
                #pragma unroll
                for (int b = 0; b < Bb; ++b) llc_load4(hv[b], hp + (size_t)b*Hh + k0);
                vm0();
                #pragma unroll
                for (int c = 0; c < CPW; ++c) {
                    const f32x4 w1 = wB[c];
                    #pragma unroll
                    for (int b = 0; b < Bb; ++b) {
                        const f32x4 i1 = hv[b];
                        acc[c][b] += w1[0]*i1[0]; acc[c][b] += w1[1]*i1[1];
                        acc[c][b] += w1[2]*i1[2]; acc[c][b] += w1[3]*i1[3];
                    }
                }
            }
            if (tid < 64) wait_ge(f0q, tid, (unsigned)(t + 1));
            __syncthreads();
            {
                const float* ap = h0ring + (size_t)(t&(R0-1))*Bb*Hh;
                f32x4 av[Bb];
                #pragma unroll
                for (int b = 0; b < Bb; ++b) llc_load4(av[b], ap + (size_t)b*Hh + k0);
                vm0();
                #pragma unroll
                for (int c = 0; c < CPW; ++c) {
                    const f32x4 w0 = wA[c];
                    #pragma unroll
                    for (int b = 0; b < Bb; ++b) {
                        const f32x4 i0 = av[b];
                        acc[c][b] += w0[0]*i0[0]; acc[c][b] += w0[1]*i0[1];
                        acc[c][b] += w0[2]*i0[2]; acc[c][b] += w0[3]*i0[3];
                    }
                }
            }
            float v[64];
            #pragma unroll
            for (int c = 0; c < CPW; ++c)
                #pragma unroll
                for (int b = 0; b < Bb; ++b) v[b*8 + c] = acc[c][b];
            BUTTERFLY();
            red[(tid >> 6)*64 + lane] = v[0];
            __syncthreads();
            if (tid < 64) {
                const int b = tid >> 3, c = tid & 7;
                const float s = red[tid] + red[64 + tid] + red[128 + tid]
                              + red[192 + tid] + biasl[c];
                const float val = fast_tanh(s);
                wt_store1(h1ring + (size_t)(t&1)*Bb*Hh + (size_t)b*Hh
                          + colbase + c, val);
                asm volatile("s_waitcnt vmcnt(0)" ::: "memory");
                if (tid == 0)
                    __hip_atomic_store(myflag, (unsigned)(t + 1),
                                       __ATOMIC_RELAXED, __HIP_MEMORY_SCOPE_AGENT);
                out[((size_t)b*Tt + t)*Hh + colbase + c] = val;
                if (t == Tt-1)
                    out[(size_t)Bb*Tt*Hh + (size_t)(Bb + b)*Hh + colbase + c] = val;
            }
        }
    }
}

extern "C" void kernel_launch(void* const* d_in, const int* in_sizes, int n_in,
                              void* d_out, int out_size, void* d_ws, size_t ws_size,
                              hipStream_t stream) {
    const float* X   = (const float*)d_in[0];
    const float* ihw = (const float*)d_in[1];
    const float* ihb = (const float*)d_in[2];
    const float* hhw = (const float*)d_in[3];
    const float* hhb = (const float*)d_in[4];
    float* outp = (float*)d_out;
    float* wsp  = (float*)d_ws;

    const size_t hist_bytes = (size_t)Tt*Bb*Hh*sizeof(float);       // 67.1 MB
    const size_t flag_bytes = (size_t)2*WPL*sizeof(unsigned);

    if (ws_size >= hist_bytes + flag_bytes) {
        // primary: zero only the flags (history is write-before-read)
        hipMemsetAsync((char*)d_ws + hist_bytes, 0, flag_bytes, stream);
        hipLaunchKernelGGL(rnn_hist, dim3(NWG), dim3(NTHR), 0, stream,
                           X, ihw, ihb, hhw, hhb, outp, wsp);
    } else {
        // fallback: proven round-5 ring kernel
        const size_t zero_bytes = (size_t)(R0+2)*Bb*Hh*sizeof(float) + flag_bytes;
        hipMemsetAsync(d_ws, 0, zero_bytes, stream);
        hipLaunchKernelGGL(rnn_persist5, dim3(NWG), dim3(NTHR), 0, stream,
                           X, ihw, ihb, hhw, hhb, outp, wsp);
    }
}

// Round 7
// 9909.861 us; speedup vs baseline: 7.2074x; 1.0649x over previous
//
#include <hip/hip_runtime.h>
#include <math.h>

typedef float f32x4 __attribute__((ext_vector_type(4)));

#define Bb   8
#define Tt   2048
#define Hh   1024
#define NTHR 256
#define NWG  256
#define WPL  128          // workgroups per layer
#define CPW  8            // columns per workgroup
#define R0   4            // fallback ring slots
#define SUBC 4            // cumulative sub-counters per layer
#define CSTR 16           // dword stride between sub-counters (64B lines)

// ---- cache-control primitives (semantics proven rounds 3/5/6) ----
// sc0 sc1 : bypass L1+L2, read/write at the Infinity Cache (coherence point)
// sc0     : bypass L1 only; L2-cacheable (safe for write-once data)
__device__ __forceinline__ void llc_load4(f32x4& d, const float* p) {
    asm volatile("global_load_dwordx4 %0, %1, off sc0 sc1" : "=v"(d) : "v"(p));
}
__device__ __forceinline__ void l2_load4(f32x4& d, const float* p) {
    asm volatile("global_load_dwordx4 %0, %1, off sc0" : "=v"(d) : "v"(p));
}
__device__ __forceinline__ void wt_store1(float* p, float v) {   // write-through
    asm volatile("global_store_dword %0, %1, off sc0 sc1" :: "v"(p), "v"(v) : "memory");
}
__device__ __forceinline__ void vm0() {
    asm volatile("s_waitcnt vmcnt(0)" ::: "memory");
    __builtin_amdgcn_sched_barrier(0);   // rule #18: pin consumers after the wait
}
__device__ __forceinline__ float fast_tanh(float s) {
    const float e = __expf(2.f * s);
    return 1.f - 2.f / (e + 1.f);
}

// cumulative-counter wait: spin until sum of the 4 sub-counters >= thr.
// Uniform across the calling wave (all lanes load the same 4 lines).
__device__ __forceinline__ void wait_cum(const unsigned* c, unsigned thr) {
    for (;;) {
        unsigned s = __hip_atomic_load(c + 0*CSTR, __ATOMIC_RELAXED, __HIP_MEMORY_SCOPE_AGENT)
                   + __hip_atomic_load(c + 1*CSTR, __ATOMIC_RELAXED, __HIP_MEMORY_SCOPE_AGENT)
                   + __hip_atomic_load(c + 2*CSTR, __ATOMIC_RELAXED, __HIP_MEMORY_SCOPE_AGENT)
                   + __hip_atomic_load(c + 3*CSTR, __ATOMIC_RELAXED, __HIP_MEMORY_SCOPE_AGENT);
        if (s >= thr) return;
    }
}

// round-5 per-WG flag wait (fallback kernel only)
__device__ __forceinline__ void wait_ge(const unsigned long long* fq, int tid, unsigned u) {
    unsigned long long a = __hip_atomic_load(fq + tid, __ATOMIC_RELAXED,
                                             __HIP_MEMORY_SCOPE_AGENT);
    bool ok = ((unsigned)a >= u) & ((unsigned)(a >> 32) >= u);
    while (!__all(ok)) {
        __builtin_amdgcn_s_sleep(1);
        a = __hip_atomic_load(fq + tid, __ATOMIC_RELAXED, __HIP_MEMORY_SCOPE_AGENT);
        ok = ((unsigned)a >= u) & ((unsigned)(a >> 32) >= u);
    }
}

#define BUTTERFLY()                                                        \
    do {                                                                   \
        _Pragma("unroll")                                                  \
        for (int r = 0; r < 6; ++r) {                                      \
            const int bit = (lane >> r) & 1;                               \
            _Pragma("unroll")                                              \
            for (int j = 0; j < (64 >> (r + 1)); ++j) {                    \
                const float send = bit ? v[2*j]     : v[2*j + 1];          \
                const float mine = bit ? v[2*j + 1] : v[2*j];              \
                v[j] = mine + __shfl_xor(send, 1 << r, 64);                \
            }                                                              \
        }                                                                  \
    } while (0)

// =============  primary: write-once history + cumulative counters  =======
__global__ __launch_bounds__(NTHR, 1)
void rnn_hist2(const float* __restrict__ X,
               const float* __restrict__ ihw,
               const float* __restrict__ ihb,
               const float* __restrict__ hhw,
               const float* __restrict__ hhb,
               float* __restrict__ out,
               float* __restrict__ ws)
{
    __shared__ float red[4*64];
    __shared__ float biasl[CPW];

    // flush poison / prior-replay lines from this XCD's L1+L2 once per run;
    // after this, write-once data can never be stale in local caches.
    __builtin_amdgcn_fence(__ATOMIC_ACQUIRE, "agent");

    const int tid = threadIdx.x;
    const int wg  = blockIdx.x;
    const int lay = (wg >= WPL) ? 1 : 0;
    const int wgl = wg & (WPL-1);
    const int colbase = wgl * CPW;
    const int k0  = tid * 4;
    const int lane = tid & 63;

    float* h0hist = ws;                                    // [Tt][Bb][Hh]
    unsigned* c0 = (unsigned*)(ws + (size_t)Tt*Bb*Hh);     // [SUBC*CSTR]
    unsigned* c1 = c0 + SUBC*CSTR;                         // [SUBC*CSTR]
    unsigned* myc = (lay ? c1 : c0) + (wgl & (SUBC-1))*CSTR;

    // persistent weights in registers: 8 cols x 4 k (ih and hh)
    f32x4 wA[CPW], wB[CPW];
    #pragma unroll
    for (int c = 0; c < CPW; ++c) {
        const int col = colbase + c;
        wA[c] = *(const f32x4*)&ihw[((size_t)lay*Hh + col)*Hh + k0];
        wB[c] = *(const f32x4*)&hhw[((size_t)lay*Hh + col)*Hh + k0];
    }
    if (tid < CPW) {
        const int col = colbase + tid;
        biasl[tid] = ihb[lay*Hh + col] + hhb[lay*Hh + col];
    }
    __syncthreads();

    if (lay == 0) {
        // ---------------- layer 0 ----------------
        f32x4 xc[Bb];
        #pragma unroll
        for (int b = 0; b < Bb; ++b)
            xc[b] = *(const f32x4*)&X[((size_t)b*Tt + 0)*Hh + k0];

        for (int t = 0; t < Tt; ++t) {
            // 1) ih partials BEFORE the wait (hides publish->observe RT)
            float acc[CPW][Bb];
            #pragma unroll
            for (int c = 0; c < CPW; ++c) {
                const f32x4 w0 = wA[c];
                #pragma unroll
                for (int b = 0; b < Bb; ++b) {
                    const f32x4 i0 = xc[b];
                    float a = w0[0]*i0[0]; a += w0[1]*i0[1];
                    a += w0[2]*i0[2]; a += w0[3]*i0[3];
                    acc[c][b] = a;
                }
            }

            // 2) wait: all l0 peers done t-1  (C0 >= 128*t)
            if (tid < 64 && t > 0) wait_cum(c0, (unsigned)(WPL * t));
            __syncthreads();

            // 3) hh half — h0(t-1) via L2-cacheable loads (write-once data)
            if (t > 0) {
                const float* hp = h0hist + (size_t)(t-1)*Bb*Hh;
                f32x4 hv[Bb];
                #pragma unroll
                for (int b = 0; b < Bb; ++b) l2_load4(hv[b], hp + (size_t)b*Hh + k0);
                vm0();
                #pragma unroll
                for (int c = 0; c < CPW; ++c) {
                    const f32x4 w1 = wB[c];
                    #pragma unroll
                    for (int b = 0; b < Bb; ++b) {
                        const f32x4 i1 = hv[b];
                        acc[c][b] += w1[0]*i1[0]; acc[c][b] += w1[1]*i1[1];
                        acc[c][b] += w1[2]*i1[2]; acc[c][b] += w1[3]*i1[3];
                    }
                }
            }

            // 4) butterfly: lane ends with output o = lane (o = b*8 + c)
            float v[64];
            #pragma unroll
            for (int c = 0; c < CPW; ++c)
                #pragma unroll
                for (int b = 0; b < Bb; ++b) v[b*8 + c] = acc[c][b];
            BUTTERFLY();
            red[(tid >> 6)*64 + lane] = v[0];
            __syncthreads();

            // 5) combine + tanh + publish-first epilogue
            if (tid < 64) {
                const int b = tid >> 3, c = tid & 7;
                const float s = red[tid] + red[64 + tid] + red[128 + tid]
                              + red[192 + tid] + biasl[c];
                const float val = fast_tanh(s);
                wt_store1(h0hist + (size_t)t*Bb*Hh + (size_t)b*Hh + colbase + c, val);
                asm volatile("s_waitcnt vmcnt(0)" ::: "memory");
                if (tid == 0)
                    __hip_atomic_fetch_add(myc, 1u,
                                           __ATOMIC_RELAXED, __HIP_MEMORY_SCOPE_AGENT);
                if (t == Tt-1)
                    out[(size_t)Bb*Tt*Hh + (size_t)b*Hh + colbase + c] = val; // h_T[0]
            }

            // 6) X prefetch for t+1 (off critical path)
            const int tn = (t + 1 < Tt) ? (t + 1) : t;
            #pragma unroll
            for (int b = 0; b < Bb; ++b)
                xc[b] = *(const f32x4*)&X[((size_t)b*Tt + tn)*Hh + k0];
        }
    } else {
        // ---------------- layer 1 (h1 history IS ys in d_out) ----------------
        for (int t = 0; t < Tt; ++t) {
            float acc[CPW][Bb];
            #pragma unroll
            for (int c = 0; c < CPW; ++c)
                #pragma unroll
                for (int b = 0; b < Bb; ++b) acc[c][b] = 0.f;

            // stage 1: all l1 done t-1 (C1 >= 128*t) -> hh half from ys
            if (t > 0) {
                if (tid < 64) wait_cum(c1, (unsigned)(WPL * t));
                __syncthreads();
                f32x4 hv[Bb];
                #pragma unroll
                for (int b = 0; b < Bb; ++b)
                    l2_load4(hv[b], out + ((size_t)b*Tt + (t-1))*Hh + k0);
                vm0();
                #pragma unroll
                for (int c = 0; c < CPW; ++c) {
                    const f32x4 w1 = wB[c];
                    #pragma unroll
                    for (int b = 0; b < Bb; ++b) {
                        const f32x4 i1 = hv[b];
                        acc[c][b] += w1[0]*i1[0]; acc[c][b] += w1[1]*i1[1];
                        acc[c][b] += w1[2]*i1[2]; acc[c][b] += w1[3]*i1[3];
                    }
                }
            }

            // stage 2: all l0 done t (C0 >= 128*(t+1)) -> ih half
            if (tid < 64) wait_cum(c0, (unsigned)(WPL * (t + 1)));
            __syncthreads();
            {
                const float* ap = h0hist + (size_t)t*Bb*Hh;
                f32x4 av[Bb];
                #pragma unroll
                for (int b = 0; b < Bb; ++b) l2_load4(av[b], ap + (size_t)b*Hh + k0);
                vm0();
                #pragma unroll
                for (int c = 0; c < CPW; ++c) {
                    const f32x4 w0 = wA[c];
                    #pragma unroll
                    for (int b = 0; b < Bb; ++b) {
                        const f32x4 i0 = av[b];
                        acc[c][b] += w0[0]*i0[0]; acc[c][b] += w0[1]*i0[1];
                        acc[c][b] += w0[2]*i0[2]; acc[c][b] += w0[3]*i0[3];
                    }
                }
            }

            // butterfly
            float v[64];
            #pragma unroll
            for (int c = 0; c < CPW; ++c)
                #pragma unroll
                for (int b = 0; b < Bb; ++b) v[b*8 + c] = acc[c][b];
            BUTTERFLY();
            red[(tid >> 6)*64 + lane] = v[0];
            __syncthreads();

            // combine + tanh; ys store IS the h1 publish data (write-through)
            if (tid < 64) {
                const int b = tid >> 3, c = tid & 7;
                const float s = red[tid] + red[64 + tid] + red[128 + tid]
                              + red[192 + tid] + biasl[c];
                const float val = fast_tanh(s);
                wt_store1(out + ((size_t)b*Tt + t)*Hh + colbase + c, val);
                asm volatile("s_waitcnt vmcnt(0)" ::: "memory");
                if (tid == 0)
                    __hip_atomic_fetch_add(myc, 1u,
                                           __ATOMIC_RELAXED, __HIP_MEMORY_SCOPE_AGENT);
                if (t == Tt-1)
                    out[(size_t)Bb*Tt*Hh + (size_t)(Bb + b)*Hh + colbase + c] = val; // h_T[1]
            }
        }
    }
}

// =====================  fallback: round-5 ring kernel (proven)  ==========
__global__ __launch_bounds__(NTHR, 1)
void rnn_persist5(const float* __restrict__ X,
                  const float* __restrict__ ihw,
                  const float* __restrict__ ihb,
                  const float* __restrict__ hhw,
                  const float* __restrict__ hhb,
                  float* __restrict__ out,
                  float* __restrict__ ws)
{
    __shared__ float red[4*64];
    __shared__ float biasl[CPW];
    const int tid = threadIdx.x;
    const int wg  = blockIdx.x;
    const int lay = (wg >= WPL) ? 1 : 0;
    const int wgl = wg & (WPL-1);
    const int colbase = wgl * CPW;
    const int k0  = tid * 4;
    const int lane = tid & 63;

    float* h0ring = ws;
    float* h1ring = ws + (size_t)R0*Bb*Hh;
    unsigned* flags0 = (unsigned*)(ws + (size_t)(R0+2)*Bb*Hh);
    unsigned* flags1 = flags0 + WPL;
    const unsigned long long* f0q = (const unsigned long long*)flags0;
    const unsigned long long* f1q = (const unsigned long long*)flags1;
    unsigned* myflag = (lay ? flags1 : flags0) + wgl;

    f32x4 wA[CPW], wB[CPW];
    #pragma unroll
    for (int c = 0; c < CPW; ++c) {
        const int col = colbase + c;
        wA[c] = *(const f32x4*)&ihw[((size_t)lay*Hh + col)*Hh + k0];
        wB[c] = *(const f32x4*)&hhw[((size_t)lay*Hh + col)*Hh + k0];
    }
    if (tid < CPW) {
        const int col = colbase + tid;
        biasl[tid] = ihb[lay*Hh + col] + hhb[lay*Hh + col];
    }
    __syncthreads();

    if (lay == 0) {
        f32x4 xc[Bb];
        #pragma unroll
        for (int b = 0; b < Bb; ++b)
            xc[b] = *(const f32x4*)&X[((size_t)b*Tt + 0)*Hh + k0];
        for (int t = 0; t < Tt; ++t) {
            float acc[CPW][Bb];
            #pragma unroll
            for (int c = 0; c < CPW; ++c) {
                const f32x4 w0 = wA[c];
                #pragma unroll
                for (int b = 0; b < Bb; ++b) {
                    const f32x4 i0 = xc[b];
                    float a = w0[0]*i0[0]; a += w0[1]*i0[1];
                    a += w0[2]*i0[2]; a += w0[3]*i0[3];
                    acc[c][b] = a;
                }
            }
            if (tid < 64 && t > 0) {
                wait_ge(f0q, tid, (unsigned)t);
                const int tB = t - (R0 - 1);
                if (tB > 0) wait_ge(f1q, tid, (unsigned)tB);
            }
            __syncthreads();
            if (t > 0) {
                const float* hp = h0ring + (size_t)((t-1)&(R0-1))*Bb*Hh;
                f32x4 hv[Bb];
                #pragma unroll
                for (int b = 0; b < Bb; ++b) llc_load4(hv[b], hp + (size_t)b*Hh + k0);
                vm0();
                #pragma unroll
                for (int c = 0; c < CPW; ++c) {
                    const f32x4 w1 = wB[c];
                    #pragma unroll
                    for (int b = 0; b < Bb; ++b) {
                        const f32x4 i1 = hv[b];
                        acc[c][b] += w1[0]*i1[0]; acc[c][b] += w1[1]*i1[1];
                        acc[c][b] += w1[2]*i1[2]; acc[c][b] += w1[3]*i1[3];
                    }
                }
            }
            float v[64];
            #pragma unroll
            for (int c = 0; c < CPW; ++c)
                #pragma unroll
                for (int b = 0; b < Bb; ++b) v[b*8 + c] = acc[c][b];
            BUTTERFLY();
            red[(tid >> 6)*64 + lane] = v[0];
            __syncthreads();
            if (tid < 64) {
                const int b = tid >> 3, c = tid & 7;
                const float s = red[tid] + red[64 + tid] + red[128 + tid]
                              + red[192 + tid] + biasl[c];
                const float val = fast_tanh(s);
                wt_store1(h0ring + (size_t)(t&(R0-1))*Bb*Hh + (size_t)b*Hh
                          + colbase + c, val);
                asm volatile("s_waitcnt vmcnt(0)" ::: "memory");
                if (tid == 0)
                    __hip_atomic_store(myflag, (unsigned)(t + 1),
                                       __ATOMIC_RELAXED, __HIP_MEMORY_SCOPE_AGENT);
                if (t == Tt-1)
                    out[(size_t)Bb*Tt*Hh + (size_t)b*Hh + colbase + c] = val;
            }
            const int tn = (t + 1 < Tt) ? (t + 1) : t;
            #pragma unroll
            for (int b = 0; b < Bb; ++b)
                xc[b] = *(const f32x4*)&X[((size_t)b*Tt + tn)*Hh + k0];
        }
    } else {
        for (int t = 0; t < Tt; ++t) {
            float acc[CPW][Bb];
            #pragma unroll
            for (int c = 0; c < CPW; ++c)
                #pragma unroll
                for (int b = 0; b < Bb; ++b) acc[c][b] = 0.f;
            if (t > 0) {
                if (tid < 64) wait_ge(f1q, tid, (unsigned)t);
                __syncthreads();
                const float* hp = h1ring + (size_t)((t-1)&1)*Bb*Hh;
                f32x4 hv[Bb];
                #pragma unroll
                for (int b = 0; b < Bb; ++b) llc_load4(hv[b], hp + (size_t)b*Hh + k0);
                vm0();
                #pragma unroll
                for (int c = 0; c < CPW; ++c) {
                    const f32x4 w1 = wB[c];
                    #pragma unroll
                    for (int b = 0; b < Bb; ++b) {
                        const f32x4 i1 = hv[b];
                        acc[c][b] += w1[0]*i1[0]; acc[c][b] += w1[1]*i1[1];
                        acc[c][b] += w1[2]*i1[2]; acc[c][b] += w1[3]*i1[3];
                    }
                }
            }
            if (tid < 64) wait_ge(f0q, tid, (unsigned)(t + 1));
            __syncthreads();
            {
                const float* ap = h0ring + (size_t)(t&(R0-1))*Bb*Hh;
                f32x4 av[Bb];
                #pragma unroll
                for (int b = 0; b < Bb; ++b) llc_load4(av[b], ap + (size_t)b*Hh + k0);
                vm0();
                #pragma unroll
                for (int c = 0; c < CPW; ++c) {
                    const f32x4 w0 = wA[c];
                    #pragma unroll
                    for (int b = 0; b < Bb; ++b) {
                        const f32x4 i0 = av[b];
                        acc[c][b] += w0[0]*i0[0]; acc[c][b] += w0[1]*i0[1];
                        acc[c][b] += w0[2]*i0[2]; acc[c][b] += w0[3]*i0[3];
                    }
                }
            }
            float v[64];
            #pragma unroll
            for (int c = 0; c < CPW; ++c)
                #pragma unroll
                for (int b = 0; b < Bb; ++b) v[b*8 + c] = acc[c][b];
            BUTTERFLY();
            red[(tid >> 6)*64 + lane] = v[0];
            __syncthreads();
            if (tid < 64) {
                const int b = tid >> 3, c = tid & 7;
                const float s = red[tid] + red[64 + tid] + red[128 + tid]
                              + red[192 + tid] + biasl[c];
                const float val = fast_tanh(s);
                wt_store1(h1ring + (size_t)(t&1)*Bb*Hh + (size_t)b*Hh
                          + colbase + c, val);
                asm volatile("s_waitcnt vmcnt(0)" ::: "memory");
                if (tid == 0)
                    __hip_atomic_store(myflag, (unsigned)(t + 1),
                                       __ATOMIC_RELAXED, __HIP_MEMORY_SCOPE_AGENT);
                out[((size_t)b*Tt + t)*Hh + colbase + c] = val;
                if (t == Tt-1)
                    out[(size_t)Bb*Tt*Hh + (size_t)(Bb + b)*Hh + colbase + c] = val;
            }
        }
    }
}

extern "C" void kernel_launch(void* const* d_in, const int* in_sizes, int n_in,
                              void* d_out, int out_size, void* d_ws, size_t ws_size,
                              hipStream_t stream) {
    const float* X   = (const float*)d_in[0];
    const float* ihw = (const float*)d_in[1];
    const float* ihb = (const float*)d_in[2];
    const float* hhw = (const float*)d_in[3];
    const float* hhb = (const float*)d_in[4];
    float* outp = (float*)d_out;
    float* wsp  = (float*)d_ws;

    const size_t hist_bytes = (size_t)Tt*Bb*Hh*sizeof(float);       // 67.1 MB
    const size_t cnt_bytes  = (size_t)2*SUBC*CSTR*sizeof(unsigned); // 512 B

    if (ws_size >= hist_bytes + cnt_bytes) {
        // primary: zero only the counters (history is write-before-read)
        hipMemsetAsync((char*)d_ws + hist_bytes, 0, cnt_bytes, stream);
        hipLaunchKernelGGL(rnn_hist2, dim3(NWG), dim3(NTHR), 0, stream,
                           X, ihw, ihb, hhw, hhb, outp, wsp);
    } else {
        // fallback: proven round-5 ring kernel
        const size_t zero_bytes = (size_t)(R0+2)*Bb*Hh*sizeof(float)
                                + (size_t)2*WPL*sizeof(unsigned);
        hipMemsetAsync(d_ws, 0, zero_bytes, stream);
        hipLaunchKernelGGL(rnn_persist5, dim3(NWG), dim3(NTHR), 0, stream,
                           X, ihw, ihb, hhw, hhb, outp, wsp);
    }
}